// Round 9
// baseline (2914.859 us; speedup 1.0000x reference)
//
#include <hip/hip_runtime.h>
#include <stdint.h>

// ---------------- types ----------------
typedef short bf16x8 __attribute__((ext_vector_type(8)));
typedef float f32x16 __attribute__((ext_vector_type(16)));
typedef float f32x4  __attribute__((ext_vector_type(4)));
typedef float f32x2  __attribute__((ext_vector_type(2)));

#define NODES  2
#define LAYERS 4
#define HD     256
#define MTILE  128   // 4 tiles x 32 rows; block = 128 threads = 2 waves

__device__ __forceinline__ unsigned short f2bf(float f) {  // RNE f32->bf16
  unsigned u = __float_as_uint(f);
  u += 0x7fffu + ((u >> 16) & 1u);
  return (unsigned short)(u >> 16);
}
__device__ __forceinline__ float elu1(float v) {
  return v > 0.0f ? v : (__expf(v) - 1.0f);
}
__device__ __forceinline__ unsigned cvtpk(float lo, float hi) {  // low16=bf16(lo)
  unsigned r;
  asm("v_cvt_pk_bf16_f32 %0, %1, %2" : "=v"(r) : "v"(lo), "v"(hi));
  return r;
}
union U8 { bf16x8 v; unsigned u[4]; };

#define MM(af, hf, a) a = __builtin_amdgcn_mfma_f32_32x32x16_bf16(af, hf, a, 0, 0, 0)

// Blob layout (identical to rounds 3-8, verified): per (node,layer) 128KB:
// [qq(4)][kc(4)][g(2)][nf(8)][l31(32)] x 16B frags; frag elem i holds
// k = 64qq+16kc+4g+(i&3)+8(i>>2) (sigma perm; D-frag j-order == B-frag i-order).
__global__ __launch_bounds__(256) void convw_kernel(const float* __restrict__ w_hid,
                                                    unsigned short* __restrict__ blob) {
  int e = blockIdx.x * 256 + threadIdx.x;
  int nl = e >> 16;
  int k  = (e >> 8) & 255;
  int n  = e & 255;
  float v = w_hid[(nl * 256 + k) * 256 + n];
  int qq  = k >> 6;
  int kc  = (k >> 4) & 3;
  int k16 = k & 15;
  int g   = (k16 >> 2) & 1;
  int i   = (k16 & 3) | ((k16 >> 3) << 2);
  int nf  = n >> 5, l31 = n & 31;
  unsigned boff = ((unsigned)(nl * 4 + qq) << 15)
                + ((unsigned)kc << 13) + ((unsigned)g << 12)
                + ((unsigned)nf << 9) + ((unsigned)l31 << 4) + ((unsigned)i << 1);
  blob[boff >> 1] = f2bf(v);
}

// ---------------- main: weight-stationary ----------------
// 2 waves/block; wave w owns nf in [4w,4w+4) (n slice of 128). W for one layer
// lives in 256 VGPRs, reused across 4 row-tiles. h lives in LDS as ready-made
// B-frags [t][kc][g][r]x16B (in-place across layers, per-tile barriers). One
// h-frag read feeds 4 MFMAs -> LDS pipe finally under the matrix pipe.
__global__ __launch_bounds__(128, 1) void nld_kernel(
    const float* __restrict__ uv, const float* __restrict__ w_in,
    const float* __restrict__ b_in, const float* __restrict__ b_hid,
    const float* __restrict__ w_out, const float* __restrict__ b_out,
    const unsigned short* __restrict__ blob, float* __restrict__ out, int nrows) {

  __shared__ __attribute__((aligned(16))) char h_lds[4 * 16 * 2 * 32 * 16];    // 64KB
  __shared__ __attribute__((aligned(16))) float pb_hid[NODES * LAYERS * HD];   // 8KB
  __shared__ __attribute__((aligned(16))) float pb_in[NODES * HD];             // 2KB
  __shared__ __attribute__((aligned(8)))  unsigned short pb_wout[NODES * HD * 2]; // 2KB
  __shared__ __attribute__((aligned(8)))  float xbuf[4][32][2];                // 1KB

  const int t    = threadIdx.x;       // 0..127
  const int lane = t & 63;
  const int wv   = t >> 6;            // 0..1
  const int l31  = lane & 31;
  const int g    = lane >> 5;
  const int nfb  = 4 * wv;            // nf base of this wave
  const unsigned hbase = (unsigned)(g * 512 + l31 * 16);
  const long rbase = (long)blockIdx.x * MTILE + l31;

  bf16x8 wreg[16][4];                 // 256 VGPRs: one layer's W slice
  auto loadW = [&](int nli) {         // nli = nd*4+ly
    const char* base = (const char*)blob + (size_t)nli * 131072
                     + (unsigned)(nfb * 512) + (unsigned)(g * 4096 + l31 * 16);
#pragma unroll
    for (int kc = 0; kc < 16; ++kc)
#pragma unroll
      for (int nl = 0; nl < 4; ++nl)
        wreg[kc][nl] = *(const bf16x8*)(base + (kc >> 2) * 32768 + (kc & 3) * 8192 + nl * 512);
  };

  loadW(0);                            // node0/layer0 in flight during prologue
  for (int i = t; i < NODES * LAYERS * HD; i += 128) pb_hid[i] = b_hid[i];
  for (int i = t; i < NODES * HD; i += 128) pb_in[i] = b_in[i];
  for (int i = t; i < NODES * HD * 2; i += 128) pb_wout[i] = f2bf(w_out[i]);

  float x0[4], x1[4];
#pragma unroll
  for (int tt = 0; tt < 4; ++tt) {
    f32x2 u = *(const f32x2*)(uv + (rbase + tt * 32) * 2);
    x0[tt] = u[0]; x1[tt] = u[1];
  }
  __syncthreads();

  f32x16 acc[4];
  uint4 pk[4][2];

  auto binit = [&](const float* bl) {  // acc := bias (D-layout: n from reg j + 4g)
#pragma unroll
    for (int nl = 0; nl < 4; ++nl) {
      int nb = 32 * (nfb + nl) + 4 * g;
      f32x4 b0 = *(const f32x4*)(bl + nb);
      f32x4 b1 = *(const f32x4*)(bl + nb + 8);
      f32x4 b2 = *(const f32x4*)(bl + nb + 16);
      f32x4 b3 = *(const f32x4*)(bl + nb + 24);
#pragma unroll
      for (int j = 0; j < 4; ++j) {
        acc[nl][j]      = b0[j];
        acc[nl][4 + j]  = b1[j];
        acc[nl][8 + j]  = b2[j];
        acc[nl][12 + j] = b3[j];
      }
    }
  };
  auto tpack = [&]() {                 // ELU + bf16 pack (regs j0..7 == frag kc=2nf)
#pragma unroll
    for (int nl = 0; nl < 4; ++nl) {
      float e[16];
#pragma unroll
      for (int j = 0; j < 16; ++j) e[j] = elu1(acc[nl][j]);
      pk[nl][0].x = cvtpk(e[0], e[1]);  pk[nl][0].y = cvtpk(e[2], e[3]);
      pk[nl][0].z = cvtpk(e[4], e[5]);  pk[nl][0].w = cvtpk(e[6], e[7]);
      pk[nl][1].x = cvtpk(e[8], e[9]);  pk[nl][1].y = cvtpk(e[10], e[11]);
      pk[nl][1].z = cvtpk(e[12], e[13]); pk[nl][1].w = cvtpk(e[14], e[15]);
    }
  };
  auto twrite = [&](int ttt) {         // store frags (kc = 8wv+2nl+half)
#pragma unroll
    for (int nl = 0; nl < 4; ++nl) {
      char* p = h_lds + ttt * 16384 + (8 * wv + 2 * nl) * 1024 + (int)hbase;
      *(uint4*)p            = pk[nl][0];
      *(uint4*)(p + 1024)   = pk[nl][1];
    }
  };

  for (int nd = 0; nd < NODES; ++nd) {
    // ---- build W_in A-frags (k=0,1 live on g=0 elems 0,1)
    bf16x8 wi[4];
#pragma unroll
    for (int nl = 0; nl < 4; ++nl) {
      int n = 32 * (nfb + nl) + l31;
      float a = w_in[(nd * 2 + 0) * HD + n];
      float b = w_in[(nd * 2 + 1) * HD + n];
      U8 f; f.u[0] = g ? 0u : cvtpk(a, b); f.u[1] = 0; f.u[2] = 0; f.u[3] = 0;
      wi[nl] = f.v;
    }

    // ---- input layer via MFMA (4 tiles, writes h; one barrier at end)
#pragma unroll
    for (int tt = 0; tt < 4; ++tt) {
      binit(&pb_in[nd * HD]);
      U8 xf; xf.u[0] = g ? 0u : cvtpk(x0[tt], x1[tt]);
      xf.u[1] = 0; xf.u[2] = 0; xf.u[3] = 0;
#pragma unroll
      for (int nl = 0; nl < 4; ++nl) MM(wi[nl], xf.v, acc[nl]);
      tpack();
      twrite(tt);
    }
    __syncthreads();

    // ---- 4 hidden layers, weight-stationary
    for (int ly = 0; ly < LAYERS; ++ly) {
      const float* bl = &pb_hid[(nd * LAYERS + ly) * HD];
#pragma unroll
      for (int tt = 0; tt < 4; ++tt) {
        binit(bl);
#pragma unroll
        for (int kc = 0; kc < 16; ++kc) {
          bf16x8 hf = *(const bf16x8*)(h_lds + tt * 16384 + kc * 1024 + hbase);
#pragma unroll
          for (int nl = 0; nl < 4; ++nl) MM(wreg[kc][nl], hf, acc[nl]);
        }
        if (tt == 3) {                 // rolling reload: next layer's W (uniform branch)
          if (ly < LAYERS - 1)      loadW(nd * LAYERS + ly + 1);
          else if (nd == 0)         loadW(LAYERS);     // node1/layer0
        }
        tpack();                       // VALU before barrier (overlaps partner wave)
        __syncthreads();               // all reads of tile tt done
        twrite(tt);                    // in-place overwrite, next read >=3 barriers away
      }
    }

    // ---- build W_out A-frags (n=0,1 live on lanes l31<2; both g halves carry k)
    bf16x8 wof[16];
#pragma unroll
    for (int kc = 0; kc < 16; ++kc) {
      U8 f;
#pragma unroll
      for (int q = 0; q < 4; ++q) {
        int i0 = 2 * q, i1 = 2 * q + 1;
        int k0 = 16 * kc + 4 * g + (i0 & 3) + 8 * (i0 >> 2);
        int k1 = 16 * kc + 4 * g + (i1 & 3) + 8 * (i1 >> 2);
        unsigned v0 = pb_wout[(nd * HD + k0) * 2 + (l31 & 1)];
        unsigned v1 = pb_wout[(nd * HD + k1) * 2 + (l31 & 1)];
        f.u[q] = (l31 < 2) ? (v0 | (v1 << 16)) : 0u;
      }
      wof[kc] = f.v;
    }

    // ---- output layer via MFMA: wave w handles tiles {2w, 2w+1}
    float bo0 = b_out[nd * 2 + 0], bo1 = b_out[nd * 2 + 1];
    float nxa0, nxa1, nxb0, nxb1;
#pragma unroll
    for (int oi = 0; oi < 2; ++oi) {
      int ot = 2 * wv + oi;
      f32x16 ao;
#pragma unroll
      for (int j = 0; j < 16; ++j) ao[j] = 0.0f;
#pragma unroll
      for (int kc = 0; kc < 16; ++kc) {
        bf16x8 hf = *(const bf16x8*)(h_lds + ot * 16384 + kc * 1024 + hbase);
        MM(wof[kc], hf, ao);
      }
      // D: n=0 -> reg 0 (g=0), n=1 -> reg 1 (g=0); lane l31 = row
      float o0 = x0[ot] + ao[0] + bo0;
      float o1 = x1[ot] + ao[1] + bo1;
      if (oi == 0) { nxa0 = o0; nxa1 = o1; } else { nxb0 = o0; nxb1 = o1; }
    }

    if (nd == 0) {                     // residual exchange via xbuf
      if (g == 0) {
        f32x2 r;
        r[0] = nxa0; r[1] = nxa1; *(f32x2*)&xbuf[2 * wv + 0][l31][0] = r;
        r[0] = nxb0; r[1] = nxb1; *(f32x2*)&xbuf[2 * wv + 1][l31][0] = r;
      }
      __syncthreads();
#pragma unroll
      for (int tt = 0; tt < 4; ++tt) { x0[tt] = xbuf[tt][l31][0]; x1[tt] = xbuf[tt][l31][1]; }
    } else {                           // final store
      if (g == 0) {
        f32x2 r;
        r[0] = nxa0; r[1] = nxa1;
        *(f32x2*)(out + (rbase + (2 * wv + 0) * 32) * 2) = r;
        r[0] = nxb0; r[1] = nxb1;
        *(f32x2*)(out + (rbase + (2 * wv + 1) * 32) * 2) = r;
      }
    }
  }
}

// ---------------- launcher ----------------
extern "C" void kernel_launch(void* const* d_in, const int* in_sizes, int n_in,
                              void* d_out, int out_size, void* d_ws, size_t ws_size,
                              hipStream_t stream) {
  const float* uv    = (const float*)d_in[0];
  const float* w_in  = (const float*)d_in[1];
  const float* b_in  = (const float*)d_in[2];
  const float* w_hid = (const float*)d_in[3];
  const float* b_hid = (const float*)d_in[4];
  const float* w_out = (const float*)d_in[5];
  const float* b_out = (const float*)d_in[6];
  unsigned short* blob = (unsigned short*)d_ws;   // 1 MB bf16 permuted blob

  int whid_elems = in_sizes[3];                   // 524288
  convw_kernel<<<whid_elems / 256, 256, 0, stream>>>(w_hid, blob);

  int N = in_sizes[0] / 2;                        // 1048576 rows
  int grid = (N + MTILE - 1) / MTILE;             // 8192 (exact: 8192*128 = 2^20)
  nld_kernel<<<grid, 128, 0, stream>>>(uv, w_in, b_in, b_hid, w_out, b_out,
                                       blob, (float*)d_out, N);
}

// Round 10
// 1423.258 us; speedup vs baseline: 2.0480x; 2.0480x over previous
//
#include <hip/hip_runtime.h>
#include <stdint.h>

// ---------------- types ----------------
typedef short bf16x8 __attribute__((ext_vector_type(8)));
typedef float f32x16 __attribute__((ext_vector_type(16)));
typedef float f32x4  __attribute__((ext_vector_type(4)));
typedef float f32x2  __attribute__((ext_vector_type(2)));

#define NODES  2
#define LAYERS 4
#define HD     256
#define MTILE  128   // 4 tiles x 32 rows; block = 256 threads = 4 waves

__device__ __forceinline__ float elu1(float v) {
  return v > 0.0f ? v : (__expf(v) - 1.0f);
}
__device__ __forceinline__ unsigned short f2bf(float f) {  // RNE f32->bf16
  unsigned u = __float_as_uint(f);
  u += 0x7fffu + ((u >> 16) & 1u);
  return (unsigned short)(u >> 16);
}
__device__ __forceinline__ unsigned cvtpk(float lo, float hi) {  // low16=bf16(lo)
  unsigned r;
  asm("v_cvt_pk_bf16_f32 %0, %1, %2" : "=v"(r) : "v"(lo), "v"(hi));
  return r;
}
union U8 { bf16x8 v; unsigned u[4]; uint4 q4; };

#define MM(af, hf, a) a = __builtin_amdgcn_mfma_f32_32x32x16_bf16(af, hf, a, 0, 0, 0)

// Blob layout (identical to rounds 3-9, verified): per (node,layer) 128KB:
// [qq(4)][kc(4)][g(2)][nf(8)][l31(32)] x 16B frags; frag elem i holds
// k = 64qq+16kc+4g+(i&3)+8(i>>2) (sigma perm; D-frag j-order == B-frag i-order).
__global__ __launch_bounds__(256) void convw_kernel(const float* __restrict__ w_hid,
                                                    unsigned short* __restrict__ blob) {
  int e = blockIdx.x * 256 + threadIdx.x;
  int nl = e >> 16;
  int k  = (e >> 8) & 255;
  int n  = e & 255;
  float v = w_hid[(nl * 256 + k) * 256 + n];
  int qq  = k >> 6;
  int kc  = (k >> 4) & 3;
  int k16 = k & 15;
  int g   = (k16 >> 2) & 1;
  int i   = (k16 & 3) | ((k16 >> 3) << 2);
  int nf  = n >> 5, l31 = n & 31;
  unsigned boff = ((unsigned)(nl * 4 + qq) << 15)
                + ((unsigned)kc << 13) + ((unsigned)g << 12)
                + ((unsigned)nf << 9) + ((unsigned)l31 << 4) + ((unsigned)i << 1);
  blob[boff >> 1] = f2bf(v);
}

// ---------------- main: weight-stationary, reg-sized ----------------
// 4 waves/block; wave w owns nf {2w,2w+1} (64 of 256 n). One layer's W slice =
// 32 bf16x8 = 128 VGPR, reused across 4 row-tiles. h lives in LDS as B-frags
// [tile][kc][g][l31]x16B (in-place across layers; 1 barrier per tile).
__global__ __launch_bounds__(256, 2) void nld_kernel(
    const float* __restrict__ uv, const float* __restrict__ w_in,
    const float* __restrict__ b_in, const float* __restrict__ b_hid,
    const float* __restrict__ w_out, const float* __restrict__ b_out,
    const unsigned short* __restrict__ blob, float* __restrict__ out, int nrows) {

  __shared__ __attribute__((aligned(16))) char  h_lds[4 * 16 * 1024];        // 64KB
  __shared__ __attribute__((aligned(16))) float pb_hid[NODES * LAYERS * HD]; // 8KB
  __shared__ __attribute__((aligned(8)))  float xbuf[4][32][2];              // 1KB

  const int t    = threadIdx.x;       // 0..255
  const int lane = t & 63;
  const int wv   = t >> 6;            // 0..3
  const int l31  = lane & 31;
  const int g    = lane >> 5;
  const unsigned hbase = (unsigned)(g * 512 + l31 * 16);
  const long rb = (long)blockIdx.x * MTILE + l31;   // row of lane in tile tt: rb+32*tt

  bf16x8 wreg[16][2];                 // 128 VGPR: this wave's W slice of one layer
  auto loadW = [&](int nli) {
    const char* base = (const char*)blob + (size_t)nli * 131072
                     + (unsigned)(wv * 1024 + g * 4096 + l31 * 16);
#pragma unroll
    for (int kc = 0; kc < 16; ++kc) {
      wreg[kc][0] = *(const bf16x8*)(base + (kc >> 2) * 32768 + (kc & 3) * 8192);
      wreg[kc][1] = *(const bf16x8*)(base + (kc >> 2) * 32768 + (kc & 3) * 8192 + 512);
    }
  };

  loadW(0);                           // node0/layer0 in flight during prologue
  for (int i = t; i < NODES * LAYERS * HD; i += 256) pb_hid[i] = b_hid[i];

  float x0[4], x1[4];
#pragma unroll
  for (int tt = 0; tt < 4; ++tt) {
    long r = rb + tt * 32;
    if (r < nrows) { f32x2 u = *(const f32x2*)(uv + r * 2); x0[tt] = u[0]; x1[tt] = u[1]; }
    else           { x0[tt] = 0.f; x1[tt] = 0.f; }
  }

  f32x16 acc[2];
  uint4  pk0[2], pk1[2];

  auto tpack = [&]() {                // ELU + pack (D j-order == B i-order)
#pragma unroll
    for (int nl = 0; nl < 2; ++nl) {
      float e[16];
#pragma unroll
      for (int j = 0; j < 16; ++j) e[j] = elu1(acc[nl][j]);
      uint4 a, b;
      a.x = cvtpk(e[0], e[1]);  a.y = cvtpk(e[2], e[3]);
      a.z = cvtpk(e[4], e[5]);  a.w = cvtpk(e[6], e[7]);
      b.x = cvtpk(e[8], e[9]);  b.y = cvtpk(e[10], e[11]);
      b.z = cvtpk(e[12], e[13]); b.w = cvtpk(e[14], e[15]);
      pk0[nl] = a; pk1[nl] = b;
    }
  };
  auto twrite = [&](int ttt) {        // frag kc = 4wv + 2nl + half
#pragma unroll
    for (int nl = 0; nl < 2; ++nl) {
      char* p = h_lds + ttt * 16384 + (4 * wv + 2 * nl) * 1024 + (int)hbase;
      *(uint4*)p          = pk0[nl];
      *(uint4*)(p + 1024) = pk1[nl];
    }
  };

  for (int nd = 0; nd < NODES; ++nd) {
    // ---- input layer: VALU, kk-outer (bounded pressure), writes h B-frags
#pragma unroll
    for (int kk = 0; kk < 4; ++kk) {
      int kc = 4 * wv + kk;
      int kb = 16 * kc + 4 * g;
      const float* wi = w_in + nd * 2 * HD;
      f32x4 wa0 = *(const f32x4*)(wi + kb);
      f32x4 wa1 = *(const f32x4*)(wi + kb + 8);
      f32x4 wb0 = *(const f32x4*)(wi + HD + kb);
      f32x4 wb1 = *(const f32x4*)(wi + HD + kb + 8);
      f32x4 bb0 = *(const f32x4*)(b_in + nd * HD + kb);
      f32x4 bb1 = *(const f32x4*)(b_in + nd * HD + kb + 8);
#pragma unroll
      for (int tt = 0; tt < 4; ++tt) {
        float p[8];
#pragma unroll
        for (int j = 0; j < 4; ++j) {
          p[j]     = elu1(fmaf(x1[tt], wb0[j], fmaf(x0[tt], wa0[j], bb0[j])));
          p[4 + j] = elu1(fmaf(x1[tt], wb1[j], fmaf(x0[tt], wa1[j], bb1[j])));
        }
        uint4 o;
        o.x = cvtpk(p[0], p[1]); o.y = cvtpk(p[2], p[3]);
        o.z = cvtpk(p[4], p[5]); o.w = cvtpk(p[6], p[7]);
        *(uint4*)(h_lds + tt * 16384 + kc * 1024 + hbase) = o;
      }
    }
    __syncthreads();                  // h(node input) + pb_hid visible

    // ---- 4 hidden layers, weight-stationary
    for (int ly = 0; ly < LAYERS; ++ly) {
      const float* bl = &pb_hid[(nd * LAYERS + ly) * HD];
#pragma unroll
      for (int tt = 0; tt < 4; ++tt) {
        // acc init = bias, straight from LDS quads (broadcast reads)
#pragma unroll
        for (int nl = 0; nl < 2; ++nl) {
          const float* bp = bl + 32 * (2 * wv + nl) + 4 * g;
#pragma unroll
          for (int q = 0; q < 4; ++q) {
            f32x4 b = *(const f32x4*)(bp + 8 * q);
            acc[nl][4 * q + 0] = b[0]; acc[nl][4 * q + 1] = b[1];
            acc[nl][4 * q + 2] = b[2]; acc[nl][4 * q + 3] = b[3];
          }
        }
#pragma unroll
        for (int kc = 0; kc < 16; ++kc) {
          bf16x8 hf = *(const bf16x8*)(h_lds + tt * 16384 + kc * 1024 + hbase);
          MM(wreg[kc][0], hf, acc[0]);
          MM(wreg[kc][1], hf, acc[1]);
        }
        if (tt == 3 && ly < LAYERS - 1) loadW(nd * LAYERS + ly + 1);  // WAR-safe
        tpack();                       // VALU (overlaps partner waves' MFMA)
        __syncthreads();               // all reads of tile tt done
        twrite(tt);                    // in-place; next read >= 3 barriers away
      }
    }
    __syncthreads();                   // last layer's writes visible

    // ---- output layer via MFMA: wave w handles tile w
    bf16x8 wof[16];
#pragma unroll
    for (int kc = 0; kc < 16; ++kc) {
      U8 f;
#pragma unroll
      for (int q = 0; q < 4; ++q) {
        int i0 = 2 * q, i1 = 2 * q + 1;
        int k0 = 16 * kc + 4 * g + (i0 & 3) + 8 * (i0 >> 2);
        int k1 = 16 * kc + 4 * g + (i1 & 3) + 8 * (i1 >> 2);
        float v0 = w_out[(nd * HD + k0) * 2 + (l31 & 1)];
        float v1 = w_out[(nd * HD + k1) * 2 + (l31 & 1)];
        f.u[q] = (l31 < 2) ? cvtpk(v0, v1) : 0u;
      }
      wof[kc] = f.v;
    }
    f32x16 ao;
#pragma unroll
    for (int j = 0; j < 16; ++j) ao[j] = 0.0f;
#pragma unroll
    for (int kc = 0; kc < 16; ++kc) {
      bf16x8 hf = *(const bf16x8*)(h_lds + wv * 16384 + kc * 1024 + hbase);
      MM(wof[kc], hf, ao);
    }
    float o0 = x0[wv] + ao[0] + b_out[nd * 2 + 0];   // D: n=0 -> reg0 (g=0), row=l31
    float o1 = x1[wv] + ao[1] + b_out[nd * 2 + 1];

    if (nd == 0) {                     // residual exchange: all lanes need all tiles
      if (g == 0) { f32x2 r; r[0] = o0; r[1] = o1; *(f32x2*)&xbuf[wv][l31][0] = r; }
      loadW(LAYERS);                   // node1/layer0 (wof dead, wreg dead)
      __syncthreads();
#pragma unroll
      for (int tt = 0; tt < 4; ++tt) { x0[tt] = xbuf[tt][l31][0]; x1[tt] = xbuf[tt][l31][1]; }
    } else {
      long r = rb + wv * 32;
      if (g == 0 && r < nrows) {
        f32x2 rr; rr[0] = o0; rr[1] = o1;
        *(f32x2*)(out + r * 2) = rr;
      }
    }
  }
}

// ---------------- launcher ----------------
extern "C" void kernel_launch(void* const* d_in, const int* in_sizes, int n_in,
                              void* d_out, int out_size, void* d_ws, size_t ws_size,
                              hipStream_t stream) {
  const float* uv    = (const float*)d_in[0];
  const float* w_in  = (const float*)d_in[1];
  const float* b_in  = (const float*)d_in[2];
  const float* w_hid = (const float*)d_in[3];
  const float* b_hid = (const float*)d_in[4];
  const float* w_out = (const float*)d_in[5];
  const float* b_out = (const float*)d_in[6];
  unsigned short* blob = (unsigned short*)d_ws;   // 1 MB bf16 permuted blob

  int whid_elems = in_sizes[3];                   // 524288
  convw_kernel<<<whid_elems / 256, 256, 0, stream>>>(w_hid, blob);

  int N = in_sizes[0] / 2;                        // 1048576 rows
  int grid = (N + MTILE - 1) / MTILE;             // 8192
  nld_kernel<<<grid, 256, 0, stream>>>(uv, w_in, b_in, b_hid, w_out, b_out,
                                       blob, (float*)d_out, N);
}

// Round 11
// 1396.888 us; speedup vs baseline: 2.0867x; 1.0189x over previous
//
#include <hip/hip_runtime.h>
#include <stdint.h>

// ---------------- types ----------------
typedef short bf16x8 __attribute__((ext_vector_type(8)));
typedef float f32x16 __attribute__((ext_vector_type(16)));
typedef float f32x4  __attribute__((ext_vector_type(4)));
typedef float f32x2  __attribute__((ext_vector_type(2)));

#define NODES  2
#define LAYERS 4
#define HD     256
#define MTILE  128   // 4 tiles x 32 rows; block = 256 threads = 4 waves

__device__ __forceinline__ float elu1(float v) {
  return v > 0.0f ? v : (__expf(v) - 1.0f);
}
__device__ __forceinline__ unsigned short f2bf(float f) {  // RNE f32->bf16
  unsigned u = __float_as_uint(f);
  u += 0x7fffu + ((u >> 16) & 1u);
  return (unsigned short)(u >> 16);
}
__device__ __forceinline__ unsigned cvtpk(float lo, float hi) {  // low16=bf16(lo)
  unsigned r;
  asm("v_cvt_pk_bf16_f32 %0, %1, %2" : "=v"(r) : "v"(lo), "v"(hi));
  return r;
}
union U8 { bf16x8 v; unsigned u[4]; uint4 q4; };

#define MM(af, hf, a) a = __builtin_amdgcn_mfma_f32_32x32x16_bf16(af, hf, a, 0, 0, 0)

// Blob layout (identical to rounds 3-10, verified): per (node,layer) 128KB:
// [qq(4)][kc(4)][g(2)][nf(8)][l31(32)] x 16B frags; frag elem i holds
// k = 64qq+16kc+4g+(i&3)+8(i>>2) (sigma perm; D-frag j-order == B-frag i-order).
__global__ __launch_bounds__(256) void convw_kernel(const float* __restrict__ w_hid,
                                                    unsigned short* __restrict__ blob) {
  int e = blockIdx.x * 256 + threadIdx.x;
  int nl = e >> 16;
  int k  = (e >> 8) & 255;
  int n  = e & 255;
  float v = w_hid[(nl * 256 + k) * 256 + n];
  int qq  = k >> 6;
  int kc  = (k >> 4) & 3;
  int k16 = k & 15;
  int g   = (k16 >> 2) & 1;
  int i   = (k16 & 3) | ((k16 >> 3) << 2);
  int nf  = n >> 5, l31 = n & 31;
  unsigned boff = ((unsigned)(nl * 4 + qq) << 15)
                + ((unsigned)kc << 13) + ((unsigned)g << 12)
                + ((unsigned)nf << 9) + ((unsigned)l31 << 4) + ((unsigned)i << 1);
  blob[boff >> 1] = f2bf(v);
}

// ---------------- main: weight-stationary, spill-free ----------------
// 4 waves/block; wave w owns nf {2w,2w+1}. One layer's W slice = 32 bf16x8 =
// 128 VGPR (all indices compile-time). h lives in LDS as ready-made B-frags
// [tile][kc][g][l31]x16B. Residual x lives in LDS xrow[128][2] — NO runtime-
// indexed register arrays anywhere (rule #20 was round 9/10's spill source).
__global__ __launch_bounds__(256, 2) void nld_kernel(
    const float* __restrict__ uv, const float* __restrict__ w_in,
    const float* __restrict__ b_in, const float* __restrict__ b_hid,
    const float* __restrict__ w_out, const float* __restrict__ b_out,
    const unsigned short* __restrict__ blob, float* __restrict__ out, int nrows) {

  __shared__ __attribute__((aligned(16))) char  h_lds[4 * 16 * 1024];        // 64KB
  __shared__ __attribute__((aligned(16))) float pb_hid[NODES * LAYERS * HD]; // 8KB
  __shared__ __attribute__((aligned(8)))  float xrow[MTILE][2];              // 1KB

  const int t    = threadIdx.x;       // 0..255
  const int lane = t & 63;
  const int wv   = t >> 6;            // 0..3
  const int l31  = lane & 31;
  const int g    = lane >> 5;
  const unsigned hbase = (unsigned)(g * 512 + l31 * 16);
  const long rb = (long)blockIdx.x * MTILE;       // block row base (grid exact)

  bf16x8 wreg[16][2];                 // 128 VGPR: this wave's W slice of one layer
  auto loadW = [&](int nli) {
    const char* base = (const char*)blob + (size_t)nli * 131072
                     + (unsigned)(wv * 1024 + g * 4096 + l31 * 16);
#pragma unroll
    for (int kc = 0; kc < 16; ++kc) {
      wreg[kc][0] = *(const bf16x8*)(base + (kc >> 2) * 32768 + (kc & 3) * 8192);
      wreg[kc][1] = *(const bf16x8*)(base + (kc >> 2) * 32768 + (kc & 3) * 8192 + 512);
    }
  };

  loadW(0);                           // node0/layer0 in flight during prologue
  for (int i = t; i < NODES * LAYERS * HD; i += 256) pb_hid[i] = b_hid[i];
  ((float*)xrow)[t] = uv[(size_t)blockIdx.x * 256 + t];   // 256 floats = 128 rows
  __syncthreads();

  f32x16 acc[2];
  uint4  pk0[2], pk1[2];

  auto tpack = [&]() {                // ELU + pack (D j-order == B i-order)
#pragma unroll
    for (int nl = 0; nl < 2; ++nl) {
      float e[16];
#pragma unroll
      for (int j = 0; j < 16; ++j) e[j] = elu1(acc[nl][j]);
      uint4 a, b;
      a.x = cvtpk(e[0], e[1]);  a.y = cvtpk(e[2], e[3]);
      a.z = cvtpk(e[4], e[5]);  a.w = cvtpk(e[6], e[7]);
      b.x = cvtpk(e[8], e[9]);  b.y = cvtpk(e[10], e[11]);
      b.z = cvtpk(e[12], e[13]); b.w = cvtpk(e[14], e[15]);
      pk0[nl] = a; pk1[nl] = b;
    }
  };
  auto twrite = [&](int ttt) {        // frag kc = 4wv + 2nl + half
#pragma unroll
    for (int nl = 0; nl < 2; ++nl) {
      char* p = h_lds + ttt * 16384 + (4 * wv + 2 * nl) * 1024 + (int)hbase;
      *(uint4*)p          = pk0[nl];
      *(uint4*)(p + 1024) = pk1[nl];
    }
  };

  for (int nd = 0; nd < NODES; ++nd) {
    // ---- input layer: VALU, kk-outer; x read from LDS with STATIC tt unroll
    float x0_[4], x1_[4];             // static-indexed only
#pragma unroll
    for (int tt = 0; tt < 4; ++tt) {
      f32x2 u = *(const f32x2*)&xrow[tt * 32 + l31][0];
      x0_[tt] = u[0]; x1_[tt] = u[1];
    }
#pragma unroll
    for (int kk = 0; kk < 4; ++kk) {
      int kc = 4 * wv + kk;
      int kb = 16 * kc + 4 * g;
      const float* wi = w_in + nd * 2 * HD;
      f32x4 wa0 = *(const f32x4*)(wi + kb);
      f32x4 wa1 = *(const f32x4*)(wi + kb + 8);
      f32x4 wb0 = *(const f32x4*)(wi + HD + kb);
      f32x4 wb1 = *(const f32x4*)(wi + HD + kb + 8);
      f32x4 bb0 = *(const f32x4*)(b_in + nd * HD + kb);
      f32x4 bb1 = *(const f32x4*)(b_in + nd * HD + kb + 8);
#pragma unroll
      for (int tt = 0; tt < 4; ++tt) {
        float p[8];
#pragma unroll
        for (int j = 0; j < 4; ++j) {
          p[j]     = elu1(fmaf(x1_[tt], wb0[j], fmaf(x0_[tt], wa0[j], bb0[j])));
          p[4 + j] = elu1(fmaf(x1_[tt], wb1[j], fmaf(x0_[tt], wa1[j], bb1[j])));
        }
        uint4 o;
        o.x = cvtpk(p[0], p[1]); o.y = cvtpk(p[2], p[3]);
        o.z = cvtpk(p[4], p[5]); o.w = cvtpk(p[6], p[7]);
        *(uint4*)(h_lds + tt * 16384 + kc * 1024 + hbase) = o;
      }
    }
    __syncthreads();                  // h(node input) visible

    // ---- 4 hidden layers, weight-stationary
    for (int ly = 0; ly < LAYERS; ++ly) {
      const float* bl = &pb_hid[(nd * LAYERS + ly) * HD];
#pragma unroll
      for (int tt = 0; tt < 4; ++tt) {
        // acc init = bias (broadcast LDS reads)
#pragma unroll
        for (int nl = 0; nl < 2; ++nl) {
          const float* bp = bl + 32 * (2 * wv + nl) + 4 * g;
#pragma unroll
          for (int q = 0; q < 4; ++q) {
            f32x4 b = *(const f32x4*)(bp + 8 * q);
            acc[nl][4 * q + 0] = b[0]; acc[nl][4 * q + 1] = b[1];
            acc[nl][4 * q + 2] = b[2]; acc[nl][4 * q + 3] = b[3];
          }
        }
#pragma unroll
        for (int kc = 0; kc < 16; ++kc) {
          bf16x8 hf = *(const bf16x8*)(h_lds + tt * 16384 + kc * 1024 + hbase);
          MM(wreg[kc][0], hf, acc[0]);
          MM(wreg[kc][1], hf, acc[1]);
        }
        if (tt == 3 && ly < LAYERS - 1) loadW(nd * LAYERS + ly + 1);  // WAR-safe
        tpack();                       // VALU (overlaps partner waves' MFMA)
        __syncthreads();               // all reads of tile tt done
        twrite(tt);                    // in-place; next read >= 3 barriers away
      }
    }
    __syncthreads();                   // last layer's writes visible

    // ---- output layer via MFMA: wave w handles tile w
    bf16x8 wof[16];
#pragma unroll
    for (int kc = 0; kc < 16; ++kc) {
      U8 f;
#pragma unroll
      for (int q = 0; q < 4; ++q) {
        int i0 = 2 * q, i1 = 2 * q + 1;
        int k0 = 16 * kc + 4 * g + (i0 & 3) + 8 * (i0 >> 2);
        int k1 = 16 * kc + 4 * g + (i1 & 3) + 8 * (i1 >> 2);
        float v0 = w_out[(nd * HD + k0) * 2 + (l31 & 1)];
        float v1 = w_out[(nd * HD + k1) * 2 + (l31 & 1)];
        f.u[q] = (l31 < 2) ? cvtpk(v0, v1) : 0u;
      }
      wof[kc] = f.v;
    }
    f32x16 ao;
#pragma unroll
    for (int j = 0; j < 16; ++j) ao[j] = 0.0f;
#pragma unroll
    for (int kc = 0; kc < 16; ++kc) {
      bf16x8 hf = *(const bf16x8*)(h_lds + wv * 16384 + kc * 1024 + hbase);
      MM(wof[kc], hf, ao);
    }
    // D: n=0 -> reg0, n=1 -> reg1 (g=0 half), row = l31; x via LDS (runtime ok)
    f32x2 xo = *(const f32x2*)&xrow[wv * 32 + l31][0];
    float o0 = xo[0] + ao[0] + b_out[nd * 2 + 0];
    float o1 = xo[1] + ao[1] + b_out[nd * 2 + 1];

    if (nd == 0) {                     // residual update in LDS
      if (g == 0) { f32x2 r; r[0] = o0; r[1] = o1; *(f32x2*)&xrow[wv * 32 + l31][0] = r; }
      loadW(LAYERS);                   // node1/layer0 (wreg dead, wof dead)
      __syncthreads();                 // xrow update visible to all waves
    } else {
      long r = rb + wv * 32 + l31;
      if (g == 0 && r < nrows) {
        f32x2 rr; rr[0] = o0; rr[1] = o1;
        *(f32x2*)(out + r * 2) = rr;
      }
    }
  }
}

// ---------------- launcher ----------------
extern "C" void kernel_launch(void* const* d_in, const int* in_sizes, int n_in,
                              void* d_out, int out_size, void* d_ws, size_t ws_size,
                              hipStream_t stream) {
  const float* uv    = (const float*)d_in[0];
  const float* w_in  = (const float*)d_in[1];
  const float* b_in  = (const float*)d_in[2];
  const float* w_hid = (const float*)d_in[3];
  const float* b_hid = (const float*)d_in[4];
  const float* w_out = (const float*)d_in[5];
  const float* b_out = (const float*)d_in[6];
  unsigned short* blob = (unsigned short*)d_ws;   // 1 MB bf16 permuted blob

  int whid_elems = in_sizes[3];                   // 524288
  convw_kernel<<<whid_elems / 256, 256, 0, stream>>>(w_hid, blob);

  int N = in_sizes[0] / 2;                        // 1048576 rows
  int grid = (N + MTILE - 1) / MTILE;             // 8192 (exact: 8192*128 = 2^20)
  nld_kernel<<<grid, 256, 0, stream>>>(uv, w_in, b_in, b_hid, w_out, b_out,
                                       blob, (float*)d_out, N);
}